// Round 3
// 679.252 us; speedup vs baseline: 1.3441x; 1.3441x over previous
//
#include <hip/hip_runtime.h>

typedef unsigned short u16;
typedef unsigned int   u32;

#define DIM  1024
#define HID  2560
#define NTOK 8192
#define NEXP 4

#define BM 128
#define BN 128
#define BK 32

#define IDXCAP 16896  // 2*NTOK + NEXP*BM padding rows

typedef __attribute__((ext_vector_type(8))) short bf16x8;
typedef __attribute__((ext_vector_type(4))) float f32x4;

// ---------- helpers ----------
__device__ __forceinline__ void async16(const void* g, void* l) {
  __builtin_amdgcn_global_load_lds((const __attribute__((address_space(1))) u32*)g,
                                   (__attribute__((address_space(3))) u32*)l,
                                   16, 0, 0);
}
__device__ __forceinline__ u16 f2bf(float f) {
  union { float f; u32 u; } c; c.f = f;
  u32 u = c.u;
  return (u16)((u + 0x7fffu + ((u >> 16) & 1u)) >> 16);   // RNE
}
__device__ __forceinline__ ushort4 cvt4(float4 v) {
  ushort4 o; o.x = f2bf(v.x); o.y = f2bf(v.y); o.z = f2bf(v.z); o.w = f2bf(v.w);
  return o;
}

// ---------- zero output + routing state (poison/replay-safe) ----------
__global__ void zero_kernel(float* __restrict__ out, int n, int* __restrict__ rt) {
  int i = blockIdx.x * blockDim.x + threadIdx.x;
  if (i < 8) rt[i] = 0;  // rt[0..3]=cnt, rt[4..7]=cursor
  int n4 = n >> 2;
  int stride = gridDim.x * blockDim.x;
  float4 z = {0.f, 0.f, 0.f, 0.f};
  for (int j = i; j < n4; j += stride) ((float4*)out)[j] = z;
  if (i == 0)
    for (int j = n4 << 2; j < n; ++j) out[j] = 0.f;
}

// ---------- one-time fp32 -> bf16 conversion of w1|w3|w2 (fused, 1 dispatch) ----------
__global__ void cvt3_kernel(const float* __restrict__ w1, const float* __restrict__ w3,
                            const float* __restrict__ w2, u16* __restrict__ w1b,
                            u16* __restrict__ w3b, u16* __restrict__ w2b, int n4each) {
  int i = blockIdx.x * blockDim.x + threadIdx.x;
  if (i < n4each)
    ((ushort4*)w1b)[i] = cvt4(((const float4*)w1)[i]);
  else if (i < 2 * n4each)
    ((ushort4*)w3b)[i - n4each] = cvt4(((const float4*)w3)[i - n4each]);
  else if (i < 3 * n4each)
    ((ushort4*)w2b)[i - 2 * n4each] = cvt4(((const float4*)w2)[i - 2 * n4each]);
}

// ---------- gating: one wave per token; also counts tokens per expert ----------
__global__ void gate_kernel(const float* __restrict__ X, const float* __restrict__ GW,
                            float* __restrict__ comb, int* __restrict__ rt) {
  __shared__ int s_cnt[NEXP];
  if (threadIdx.x < NEXP) s_cnt[threadIdx.x] = 0;
  __syncthreads();

  int gtid = blockIdx.x * blockDim.x + threadIdx.x;
  int tok  = gtid >> 6;
  int lane = gtid & 63;

  const float4* xv = (const float4*)(X + (size_t)tok * DIM + lane * 16);
  float4 x0 = xv[0], x1 = xv[1], x2 = xv[2], x3 = xv[3];

  float acc[NEXP];
#pragma unroll
  for (int e = 0; e < NEXP; ++e) {
    const float4* gv = (const float4*)(GW + e * DIM + lane * 16);
    float4 g0 = gv[0], g1 = gv[1], g2 = gv[2], g3 = gv[3];
    float s;
    s  = x0.x * g0.x + x0.y * g0.y + x0.z * g0.z + x0.w * g0.w;
    s += x1.x * g1.x + x1.y * g1.y + x1.z * g1.z + x1.w * g1.w;
    s += x2.x * g2.x + x2.y * g2.y + x2.z * g2.z + x2.w * g2.w;
    s += x3.x * g3.x + x3.y * g3.y + x3.z * g3.z + x3.w * g3.w;
    acc[e] = s;
  }
#pragma unroll
  for (int off = 32; off > 0; off >>= 1) {
#pragma unroll
    for (int e = 0; e < NEXP; ++e) acc[e] += __shfl_xor(acc[e], off);
  }
  if (lane == 0) {
    int i1 = 0;
#pragma unroll
    for (int e = 1; e < NEXP; ++e) if (acc[e] > acc[i1]) i1 = e;
    int i2 = -1;
#pragma unroll
    for (int e = 0; e < NEXP; ++e) {
      if (e == i1) continue;
      if (i2 < 0 || acc[e] > acc[i2]) i2 = e;
    }
    float m  = acc[i1];
    float e1 = __expf(acc[i1] - m), e2 = __expf(acc[i2] - m);
    float inv = 1.f / (e1 + e2);
    float w[NEXP] = {0.f, 0.f, 0.f, 0.f};
    w[i1] = e1 * inv; w[i2] = e2 * inv;
#pragma unroll
    for (int e = 0; e < NEXP; ++e) comb[(size_t)tok * NEXP + e] = w[e];
    atomicAdd(&s_cnt[i1], 1);
    atomicAdd(&s_cnt[i2], 1);
  }
  __syncthreads();
  if (threadIdx.x < NEXP) atomicAdd(&rt[threadIdx.x], s_cnt[threadIdx.x]);
}

// ---------- per-expert base offsets (128-padded prefix sum over 4 counts) ----------
__global__ void scan_kernel(int* __restrict__ rt) {
  if (threadIdx.x == 0 && blockIdx.x == 0) {
    int b = 0;
#pragma unroll
    for (int e = 0; e < NEXP; ++e) {
      rt[8 + e] = b;
      b += (rt[e] + BM - 1) & ~(BM - 1);
    }
  }
}

// ---------- compact token lists per expert (ballot aggregation) ----------
__global__ void fill_kernel(const float* __restrict__ comb, int* __restrict__ rt,
                            int* __restrict__ idxpool) {
  int t    = blockIdx.x * blockDim.x + threadIdx.x;
  int lane = threadIdx.x & 63;
  float4 c = ((const float4*)comb)[t];
  float cv[NEXP] = {c.x, c.y, c.z, c.w};
#pragma unroll
  for (int e = 0; e < NEXP; ++e) {
    bool sel = cv[e] > 0.f;
    unsigned long long b = __ballot(sel);
    int cw = __popcll(b);
    int bp = 0;
    if (lane == 0 && cw) bp = atomicAdd(&rt[4 + e], cw);
    bp = __shfl(bp, 0);
    if (sel) {
      int off = __popcll(b & ((1ull << lane) - 1ull));
      idxpool[rt[8 + e] + bp + off] = t;
    }
  }
}

// ---------- GEMM1 (all experts, gathered rows): h = comb * silu(x@w1^T) * (x@w3^T) ----------
// grid = (HID/BN, 64*NEXP); blockIdx.y -> (expert, m-block); early exit past cnt[e].
__global__ __launch_bounds__(256, 2) void ffn13_kernel(
    const float* __restrict__ X, const u16* __restrict__ W1,
    const u16* __restrict__ W3, const float* __restrict__ combp,
    const int* __restrict__ idxpool, const int* __restrict__ rt,
    u16* __restrict__ Hpool) {
  const int e   = blockIdx.y >> 6;
  const int mb  = blockIdx.y & 63;
  const int cnt = rt[e];
  const int m0  = mb * BM;
  if (m0 >= cnt) return;
  const int rbase = rt[8 + e];
  const int n0    = blockIdx.x * BN;

  __shared__ __align__(16) u16 As [BM * BK];
  __shared__ __align__(16) u16 B1s[BN * BK];
  __shared__ __align__(16) u16 B3s[BN * BK];
  __shared__ float s_comb[BM];
  __shared__ int   s_idx [BM];

  const int tid  = threadIdx.x;
  const int wave = tid >> 6;
  const int lane = tid & 63;

  if (tid < BM) {
    int m = m0 + tid;
    int t = (m < cnt) ? idxpool[rbase + m] : 0;
    s_idx[tid]  = t;
    s_comb[tid] = combp[(size_t)t * NEXP + e];
  }
  __syncthreads();

  const u16* W1e = W1 + (size_t)e * HID * DIM;
  const u16* W3e = W3 + (size_t)e * HID * DIM;

  const float* gA[4]; u16* lA[4];
#pragma unroll
  for (int q = 0; q < 4; ++q) {
    int c = tid + q * 256;
    gA[q] = X + (size_t)s_idx[c >> 3] * DIM + (c & 7) * 4;
    lA[q] = &As[c * 4];
  }
  const int lr = lane >> 2;
  const int lc = (lane & 3) * 8;
  const u16* p1[2]; const u16* p3[2]; u16 *l1[2], *l3[2];
#pragma unroll
  for (int t = 0; t < 2; ++t) {
    int c = wave * 2 + t;
    p1[t] = W1e + (size_t)(n0 + c * 16 + lr) * DIM + lc;
    p3[t] = W3e + (size_t)(n0 + c * 16 + lr) * DIM + lc;
    l1[t] = &B1s[c * 512];
    l3[t] = &B3s[c * 512];
  }

  const int wm = (wave >> 1) * 64, wn = (wave & 1) * 64;
  const int quad = lane >> 4, r = lane & 15;

  f32x4 acc1[4][4], acc3[4][4];
#pragma unroll
  for (int i = 0; i < 4; ++i)
#pragma unroll
    for (int j = 0; j < 4; ++j) {
      acc1[i][j] = (f32x4){0.f, 0.f, 0.f, 0.f};
      acc3[i][j] = (f32x4){0.f, 0.f, 0.f, 0.f};
    }

  for (int k0 = 0; k0 < DIM; k0 += BK) {
    float4 va[4];
#pragma unroll
    for (int q = 0; q < 4; ++q) { va[q] = *(const float4*)gA[q]; gA[q] += BK; }

    __syncthreads();
#pragma unroll
    for (int q = 0; q < 4; ++q) *(ushort4*)lA[q] = cvt4(va[q]);
#pragma unroll
    for (int t = 0; t < 2; ++t) {
      async16(p1[t], l1[t]); p1[t] += BK;
      async16(p3[t], l3[t]); p3[t] += BK;
    }
    __syncthreads();

    bf16x8 af[4], b1f[4], b3f[4];
#pragma unroll
    for (int i = 0; i < 4; ++i)
      af[i] = *(const bf16x8*)&As[(wm + i * 16 + r) * BK + quad * 8];
#pragma unroll
    for (int j = 0; j < 4; ++j) {
      b1f[j] = *(const bf16x8*)&B1s[(wn + j * 16 + r) * BK + quad * 8];
      b3f[j] = *(const bf16x8*)&B3s[(wn + j * 16 + r) * BK + quad * 8];
    }
#pragma unroll
    for (int i = 0; i < 4; ++i)
#pragma unroll
      for (int j = 0; j < 4; ++j) {
        acc1[i][j] = __builtin_amdgcn_mfma_f32_16x16x32_bf16(af[i], b1f[j], acc1[i][j], 0, 0, 0);
        acc3[i][j] = __builtin_amdgcn_mfma_f32_16x16x32_bf16(af[i], b3f[j], acc3[i][j], 0, 0, 0);
      }
  }

#pragma unroll
  for (int i = 0; i < 4; ++i) {
    const int rowb = wm + i * 16 + quad * 4;
#pragma unroll
    for (int rr = 0; rr < 4; ++rr) {
      const float cw = s_comb[rowb + rr];
      u16* orow = Hpool + (size_t)(rbase + m0 + rowb + rr) * HID + n0 + wn + r;
#pragma unroll
      for (int j = 0; j < 4; ++j) {
        float v1v = acc1[i][j][rr];
        float v3v = acc3[i][j][rr];
        float sig = 1.f / (1.f + __expf(-v1v));
        orow[j * 16] = f2bf(cw * (v1v * sig * v3v));
      }
    }
  }
}

// ---------- GEMM2 (all experts, compact rows): out[token] += h_row @ w2_e^T ----------
// grid = 512*NEXP 1-D. Within each expert's 512-block segment, the old XCD-stripe
// swizzle survives (512 % 8 == 0): xcd = bid&7 owns an m-stripe, n cycles fastest.
__global__ __launch_bounds__(256, 2) void ffn2_kernel(
    const u16* __restrict__ Hpool, const u16* __restrict__ W2b,
    const int* __restrict__ idxpool, const int* __restrict__ rt,
    float* __restrict__ Out) {
  const int e   = blockIdx.x >> 9;
  const int bid = blockIdx.x & 511;
  const int cnt = rt[e];
  const int Mb  = (cnt + BM - 1) >> 7;
  const int xcd = bid & 7;
  const int k   = bid >> 3;
  const int mb  = xcd * 8 + (k >> 3);
  const int nb  = k & 7;
  if (mb >= Mb) return;
  const int rbase = rt[8 + e];
  const int m0 = mb * BM;
  const int n0 = nb * BN;

  __shared__ __align__(16) u16 As[BM * BK];
  __shared__ __align__(16) u16 Bs[BN * BK];
  __shared__ int s_idx[BM];

  const int tid  = threadIdx.x;
  const int wave = tid >> 6;
  const int lane = tid & 63;

  if (tid < BM) {
    int m = m0 + tid;
    s_idx[tid] = (m < cnt) ? idxpool[rbase + m] : -1;
  }

  const int lr = lane >> 2;
  const int lc = (lane & 3) * 8;
  const int c0 = wave * 2, c1 = wave * 2 + 1;
  u16* la0 = &As[c0 * 512]; u16* la1 = &As[c1 * 512];
  u16* lb0 = &Bs[c0 * 512]; u16* lb1 = &Bs[c1 * 512];

  const u16* pa0 = Hpool + (size_t)(rbase + m0 + c0 * 16 + lr) * HID + lc;
  const u16* pa1 = Hpool + (size_t)(rbase + m0 + c1 * 16 + lr) * HID + lc;
  const u16* pb0 = W2b + ((size_t)e * DIM + n0 + c0 * 16 + lr) * HID + lc;
  const u16* pb1 = W2b + ((size_t)e * DIM + n0 + c1 * 16 + lr) * HID + lc;

  const int wm = (wave >> 1) * 64, wn = (wave & 1) * 64;
  const int quad = lane >> 4, r = lane & 15;

  f32x4 acc[4][4];
#pragma unroll
  for (int i = 0; i < 4; ++i)
#pragma unroll
    for (int j = 0; j < 4; ++j) acc[i][j] = (f32x4){0.f, 0.f, 0.f, 0.f};

  for (int k0 = 0; k0 < HID; k0 += BK) {
    __syncthreads();
    async16(pa0, la0); pa0 += BK;
    async16(pa1, la1); pa1 += BK;
    async16(pb0, lb0); pb0 += BK;
    async16(pb1, lb1); pb1 += BK;
    __syncthreads();

    bf16x8 af[4], bf[4];
#pragma unroll
    for (int i = 0; i < 4; ++i)
      af[i] = *(const bf16x8*)&As[(wm + i * 16 + r) * BK + quad * 8];
#pragma unroll
    for (int j = 0; j < 4; ++j)
      bf[j] = *(const bf16x8*)&Bs[(wn + j * 16 + r) * BK + quad * 8];
#pragma unroll
    for (int i = 0; i < 4; ++i)
#pragma unroll
      for (int j = 0; j < 4; ++j)
        acc[i][j] = __builtin_amdgcn_mfma_f32_16x16x32_bf16(af[i], bf[j], acc[i][j], 0, 0, 0);
  }

#pragma unroll
  for (int i = 0; i < 4; ++i) {
    const int rowb = wm + i * 16 + quad * 4;
#pragma unroll
    for (int rr = 0; rr < 4; ++rr) {
      int t = s_idx[rowb + rr];
      if (t >= 0) {
        float* orow = Out + (size_t)t * DIM + n0 + wn + r;
#pragma unroll
        for (int j = 0; j < 4; ++j) unsafeAtomicAdd(&orow[j * 16], acc[i][j][rr]);
      }
    }
  }
}

__global__ void ws_marker_kernel(float* __restrict__ Out, float v) {
  if (threadIdx.x == 0 && blockIdx.x == 0) Out[0] = v;
}

extern "C" void kernel_launch(void* const* d_in, const int* in_sizes, int n_in,
                              void* d_out, int out_size, void* d_ws, size_t ws_size,
                              hipStream_t stream) {
  const float* x  = (const float*)d_in[0];
  const float* gw = (const float*)d_in[1];
  const float* w1 = (const float*)d_in[2];
  const float* w2 = (const float*)d_in[3];
  const float* w3 = (const float*)d_in[4];
  float* out = (float*)d_out;

  // ws layout: comb 128KiB | rt 128B | idxpool 66KiB | w1b|w3b|w2b 60MiB | Hpool 82.5MiB
  const size_t WELEMS = (size_t)NEXP * HID * DIM;
  const size_t WBYTES = WELEMS * sizeof(u16);
  char* ws = (char*)d_ws;
  float* comb    = (float*)ws;
  int*   rt      = (int*)(ws + 131072);
  int*   idxpool = (int*)(ws + 131072 + 128);
  u16*   w1b     = (u16*)(ws + 131072 + 128 + (size_t)IDXCAP * 4);
  u16*   w3b     = w1b + WELEMS;
  u16*   w2b     = w3b + WELEMS;
  u16*   Hpool   = w2b + WELEMS;

  const size_t need = 131072 + 128 + (size_t)IDXCAP * 4 + 3 * WBYTES +
                      (size_t)IDXCAP * HID * sizeof(u16);
  if (ws_size < need) {
    float v = 5000.0f + (float)((ws_size >> 20) > 999 ? 999 : (ws_size >> 20));
    ws_marker_kernel<<<dim3(1), dim3(64), 0, stream>>>(out, v);
    return;
  }

  zero_kernel<<<dim3(2048), dim3(256), 0, stream>>>(out, out_size / 4, rt);

  {
    int n4each = (int)(WELEMS / 4);
    int blocks = (3 * n4each + 255) / 256;
    cvt3_kernel<<<dim3(blocks), dim3(256), 0, stream>>>(w1, w3, w2, w1b, w3b, w2b, n4each);
  }

  gate_kernel<<<dim3(NTOK / 4), dim3(256), 0, stream>>>(x, gw, comb, rt);
  scan_kernel<<<dim3(1), dim3(64), 0, stream>>>(rt);
  fill_kernel<<<dim3(NTOK / 256), dim3(256), 0, stream>>>(comb, rt, idxpool);

  ffn13_kernel<<<dim3(HID / BN, 64 * NEXP), dim3(256), 0, stream>>>(
      x, w1b, w3b, comb, idxpool, rt, Hpool);

  ffn2_kernel<<<dim3(512 * NEXP), dim3(256), 0, stream>>>(Hpool, w2b, idxpool, rt, out);
}

// Round 4
// 567.617 us; speedup vs baseline: 1.6084x; 1.1967x over previous
//
#include <hip/hip_runtime.h>

typedef unsigned short u16;
typedef unsigned int   u32;

#define DIM  1024
#define HID  2560
#define NTOK 8192
#define NEXP 4

#define BM 128
#define BN 128
#define BK 64   // per barrier-pair; two 32-wide MFMA sub-tiles

#define IDXCAP 16896  // 2*NTOK + NEXP*BM padding rows

typedef __attribute__((ext_vector_type(8))) short bf16x8;
typedef __attribute__((ext_vector_type(4))) float f32x4;

// ---------- helpers ----------
__device__ __forceinline__ void async16(const void* g, void* l) {
  __builtin_amdgcn_global_load_lds((const __attribute__((address_space(1))) u32*)g,
                                   (__attribute__((address_space(3))) u32*)l,
                                   16, 0, 0);
}
__device__ __forceinline__ u16 f2bf(float f) {
  union { float f; u32 u; } c; c.f = f;
  u32 u = c.u;
  return (u16)((u + 0x7fffu + ((u >> 16) & 1u)) >> 16);   // RNE
}
__device__ __forceinline__ ushort4 cvt4(float4 v) {
  ushort4 o; o.x = f2bf(v.x); o.y = f2bf(v.y); o.z = f2bf(v.z); o.w = f2bf(v.w);
  return o;
}

// ---------- zero output + routing state (poison/replay-safe) ----------
__global__ void zero_kernel(float* __restrict__ out, int n, int* __restrict__ rt) {
  int i = blockIdx.x * blockDim.x + threadIdx.x;
  if (i < 8) rt[i] = 0;  // rt[0..3]=cnt, rt[4..7]=cursor
  int n4 = n >> 2;
  int stride = gridDim.x * blockDim.x;
  float4 z = {0.f, 0.f, 0.f, 0.f};
  for (int j = i; j < n4; j += stride) ((float4*)out)[j] = z;
  if (i == 0)
    for (int j = n4 << 2; j < n; ++j) out[j] = 0.f;
}

// ---------- fp32 -> bf16: w1|w3 (before ffn13) ----------
__global__ void cvt13_kernel(const float* __restrict__ w1, const float* __restrict__ w3,
                             u16* __restrict__ w1b, u16* __restrict__ w3b, int n4each) {
  int i = blockIdx.x * blockDim.x + threadIdx.x;
  if (i < n4each)
    ((ushort4*)w1b)[i] = cvt4(((const float4*)w1)[i]);
  else if (i < 2 * n4each)
    ((ushort4*)w3b)[i - n4each] = cvt4(((const float4*)w3)[i - n4each]);
}

// ---------- fp32 -> bf16: w2 (after ffn13; w2b aliases w1b) ----------
__global__ void cvt2_kernel(const float* __restrict__ w2, u16* __restrict__ w2b, int n4) {
  int i = blockIdx.x * blockDim.x + threadIdx.x;
  if (i < n4) ((ushort4*)w2b)[i] = cvt4(((const float4*)w2)[i]);
}

// ---------- gating: one wave per token; counts tokens/expert; writes Xb bf16 ----------
__global__ void gate_kernel(const float* __restrict__ X, const float* __restrict__ GW,
                            float* __restrict__ comb, int* __restrict__ rt,
                            u16* __restrict__ Xb) {
  __shared__ int s_cnt[NEXP];
  if (threadIdx.x < NEXP) s_cnt[threadIdx.x] = 0;
  __syncthreads();

  int gtid = blockIdx.x * blockDim.x + threadIdx.x;
  int tok  = gtid >> 6;
  int lane = gtid & 63;

  const float4* xv = (const float4*)(X + (size_t)tok * DIM + lane * 16);
  float4 x0 = xv[0], x1 = xv[1], x2 = xv[2], x3 = xv[3];

  // bf16 copy of X for the MFMA A-path
  ushort4* xb = (ushort4*)(Xb + (size_t)tok * DIM + lane * 16);
  xb[0] = cvt4(x0); xb[1] = cvt4(x1); xb[2] = cvt4(x2); xb[3] = cvt4(x3);

  float acc[NEXP];
#pragma unroll
  for (int e = 0; e < NEXP; ++e) {
    const float4* gv = (const float4*)(GW + e * DIM + lane * 16);
    float4 g0 = gv[0], g1 = gv[1], g2 = gv[2], g3 = gv[3];
    float s;
    s  = x0.x * g0.x + x0.y * g0.y + x0.z * g0.z + x0.w * g0.w;
    s += x1.x * g1.x + x1.y * g1.y + x1.z * g1.z + x1.w * g1.w;
    s += x2.x * g2.x + x2.y * g2.y + x2.z * g2.z + x2.w * g2.w;
    s += x3.x * g3.x + x3.y * g3.y + x3.z * g3.z + x3.w * g3.w;
    acc[e] = s;
  }
#pragma unroll
  for (int off = 32; off > 0; off >>= 1) {
#pragma unroll
    for (int e = 0; e < NEXP; ++e) acc[e] += __shfl_xor(acc[e], off);
  }
  if (lane == 0) {
    int i1 = 0;
#pragma unroll
    for (int e = 1; e < NEXP; ++e) if (acc[e] > acc[i1]) i1 = e;
    int i2 = -1;
#pragma unroll
    for (int e = 0; e < NEXP; ++e) {
      if (e == i1) continue;
      if (i2 < 0 || acc[e] > acc[i2]) i2 = e;
    }
    float m  = acc[i1];
    float e1 = __expf(acc[i1] - m), e2 = __expf(acc[i2] - m);
    float inv = 1.f / (e1 + e2);
    float w[NEXP] = {0.f, 0.f, 0.f, 0.f};
    w[i1] = e1 * inv; w[i2] = e2 * inv;
#pragma unroll
    for (int e = 0; e < NEXP; ++e) comb[(size_t)tok * NEXP + e] = w[e];
    atomicAdd(&s_cnt[i1], 1);
    atomicAdd(&s_cnt[i2], 1);
  }
  __syncthreads();
  if (threadIdx.x < NEXP) atomicAdd(&rt[threadIdx.x], s_cnt[threadIdx.x]);
}

// ---------- per-expert base offsets (128-padded prefix sum over 4 counts) ----------
__global__ void scan_kernel(int* __restrict__ rt) {
  if (threadIdx.x == 0 && blockIdx.x == 0) {
    int b = 0;
#pragma unroll
    for (int e = 0; e < NEXP; ++e) {
      rt[8 + e] = b;
      b += (rt[e] + BM - 1) & ~(BM - 1);
    }
  }
}

// ---------- compact token lists per expert (ballot aggregation) ----------
__global__ void fill_kernel(const float* __restrict__ comb, int* __restrict__ rt,
                            int* __restrict__ idxpool) {
  int t    = blockIdx.x * blockDim.x + threadIdx.x;
  int lane = threadIdx.x & 63;
  float4 c = ((const float4*)comb)[t];
  float cv[NEXP] = {c.x, c.y, c.z, c.w};
#pragma unroll
  for (int e = 0; e < NEXP; ++e) {
    bool sel = cv[e] > 0.f;
    unsigned long long b = __ballot(sel);
    int cw = __popcll(b);
    int bp = 0;
    if (lane == 0 && cw) bp = atomicAdd(&rt[4 + e], cw);
    bp = __shfl(bp, 0);
    if (sel) {
      int off = __popcll(b & ((1ull << lane) - 1ull));
      idxpool[rt[8 + e] + bp + off] = t;
    }
  }
}

// Tile staging scheme (both GEMMs): LDS tile [128 rows][64 cols] bf16, 16B chunks.
// Chunk c = tid + 256*q: row = c>>3, colchunk = c&7. LDS dest LINEAR (c*16B,
// satisfies global_load_lds wave-uniform-base + lane*16). Bank-conflict fix via
// pre-swizzled GLOBAL source: LDS(row,cc) holds G(row, cc ^ (row&7)); the MFMA
// read applies the same XOR -> all 32 banks covered, 2-way max (free).

// ---------- GEMM1: h = comb * silu(x@w1^T) * (x@w3^T), gathered rows ----------
__global__ __launch_bounds__(256, 2) void ffn13_kernel(
    const u16* __restrict__ Xb, const u16* __restrict__ W1,
    const u16* __restrict__ W3, const float* __restrict__ combp,
    const int* __restrict__ idxpool, const int* __restrict__ rt,
    u16* __restrict__ Hpool) {
  const int e   = blockIdx.y >> 6;
  const int mb  = blockIdx.y & 63;
  const int cnt = rt[e];
  const int m0  = mb * BM;
  if (m0 >= cnt) return;
  const int rbase = rt[8 + e];
  const int n0    = blockIdx.x * BN;

  __shared__ __align__(16) u16 As [BM * BK];
  __shared__ __align__(16) u16 B1s[BN * BK];
  __shared__ __align__(16) u16 B3s[BN * BK];
  __shared__ float s_comb[BM];
  __shared__ int   s_idx [BM];

  const int tid  = threadIdx.x;
  const int wave = tid >> 6;
  const int lane = tid & 63;

  if (tid < BM) {
    int m = m0 + tid;
    int t = (m < cnt) ? idxpool[rbase + m] : 0;
    s_idx[tid]  = t;
    s_comb[tid] = combp[(size_t)t * NEXP + e];
  }
  __syncthreads();

  const u16* W1e = W1 + (size_t)e * HID * DIM;
  const u16* W3e = W3 + (size_t)e * HID * DIM;

  const int scc = (((tid & 7) ^ ((tid >> 3) & 7)) << 3);  // swizzled src col (elems)
  const int r0  = tid >> 3;
  const u16 *pA[4], *pB1[4], *pB3[4];
  int dsto[4];
#pragma unroll
  for (int q = 0; q < 4; ++q) {
    int row = r0 + 32 * q;
    pA[q]   = Xb  + (size_t)s_idx[row] * DIM + scc;
    pB1[q]  = W1e + (size_t)(n0 + row) * DIM + scc;
    pB3[q]  = W3e + (size_t)(n0 + row) * DIM + scc;
    dsto[q] = (tid + 256 * q) * 8;
  }

  const int wm = (wave >> 1) * 64, wn = (wave & 1) * 64;
  const int quad = lane >> 4, r = lane & 15;

  f32x4 acc1[4][4], acc3[4][4];
#pragma unroll
  for (int i = 0; i < 4; ++i)
#pragma unroll
    for (int j = 0; j < 4; ++j) {
      acc1[i][j] = (f32x4){0.f, 0.f, 0.f, 0.f};
      acc3[i][j] = (f32x4){0.f, 0.f, 0.f, 0.f};
    }

  for (int k0 = 0; k0 < DIM; k0 += BK) {
    __syncthreads();
#pragma unroll
    for (int q = 0; q < 4; ++q) { async16(pA[q],  &As [dsto[q]]); pA[q]  += BK; }
#pragma unroll
    for (int q = 0; q < 4; ++q) { async16(pB1[q], &B1s[dsto[q]]); pB1[q] += BK; }
#pragma unroll
    for (int q = 0; q < 4; ++q) { async16(pB3[q], &B3s[dsto[q]]); pB3[q] += BK; }
    __syncthreads();

#pragma unroll
    for (int s = 0; s < 2; ++s) {
      bf16x8 af[4], b1f[4], b3f[4];
#pragma unroll
      for (int i = 0; i < 4; ++i) {
        int row = wm + i * 16 + r;
        af[i] = *(const bf16x8*)&As[row * BK + ((((s << 2) + quad) ^ (row & 7)) << 3)];
      }
#pragma unroll
      for (int j = 0; j < 4; ++j) {
        int row = wn + j * 16 + r;
        int cc  = (((s << 2) + quad) ^ (row & 7)) << 3;
        b1f[j] = *(const bf16x8*)&B1s[row * BK + cc];
        b3f[j] = *(const bf16x8*)&B3s[row * BK + cc];
      }
#pragma unroll
      for (int i = 0; i < 4; ++i)
#pragma unroll
        for (int j = 0; j < 4; ++j) {
          acc1[i][j] = __builtin_amdgcn_mfma_f32_16x16x32_bf16(af[i], b1f[j], acc1[i][j], 0, 0, 0);
          acc3[i][j] = __builtin_amdgcn_mfma_f32_16x16x32_bf16(af[i], b3f[j], acc3[i][j], 0, 0, 0);
        }
    }
  }

#pragma unroll
  for (int i = 0; i < 4; ++i) {
    const int rowb = wm + i * 16 + quad * 4;
#pragma unroll
    for (int rr = 0; rr < 4; ++rr) {
      const float cw = s_comb[rowb + rr];
      u16* orow = Hpool + (size_t)(rbase + m0 + rowb + rr) * HID + n0 + wn + r;
#pragma unroll
      for (int j = 0; j < 4; ++j) {
        float v1v = acc1[i][j][rr];
        float v3v = acc3[i][j][rr];
        float sig = 1.f / (1.f + __expf(-v1v));
        orow[j * 16] = f2bf(cw * (v1v * sig * v3v));
      }
    }
  }
}

// ---------- GEMM2: out[token] += h_row @ w2_e^T (compact rows, atomic scatter) ----------
__global__ __launch_bounds__(256, 2) void ffn2_kernel(
    const u16* __restrict__ Hpool, const u16* __restrict__ W2b,
    const int* __restrict__ idxpool, const int* __restrict__ rt,
    float* __restrict__ Out) {
  const int e   = blockIdx.x >> 9;
  const int bid = blockIdx.x & 511;
  const int cnt = rt[e];
  const int Mb  = (cnt + BM - 1) >> 7;
  const int xcd = bid & 7;
  const int k   = bid >> 3;
  const int mb  = xcd * 8 + (k >> 3);
  const int nb  = k & 7;
  if (mb >= Mb) return;
  const int rbase = rt[8 + e];
  const int m0 = mb * BM;
  const int n0 = nb * BN;

  __shared__ __align__(16) u16 As[BM * BK];
  __shared__ __align__(16) u16 Bs[BN * BK];
  __shared__ int s_idx[BM];

  const int tid  = threadIdx.x;
  const int wave = tid >> 6;
  const int lane = tid & 63;

  if (tid < BM) {
    int m = m0 + tid;
    s_idx[tid] = (m < cnt) ? idxpool[rbase + m] : -1;
  }

  const int scc = (((tid & 7) ^ ((tid >> 3) & 7)) << 3);
  const int r0  = tid >> 3;
  const u16 *pa[4], *pb[4];
  int dsto[4];
#pragma unroll
  for (int q = 0; q < 4; ++q) {
    int row = r0 + 32 * q;
    pa[q]   = Hpool + (size_t)(rbase + m0 + row) * HID + scc;
    pb[q]   = W2b + ((size_t)e * DIM + n0 + row) * HID + scc;
    dsto[q] = (tid + 256 * q) * 8;
  }

  const int wm = (wave >> 1) * 64, wn = (wave & 1) * 64;
  const int quad = lane >> 4, r = lane & 15;

  f32x4 acc[4][4];
#pragma unroll
  for (int i = 0; i < 4; ++i)
#pragma unroll
    for (int j = 0; j < 4; ++j) acc[i][j] = (f32x4){0.f, 0.f, 0.f, 0.f};

  for (int k0 = 0; k0 < HID; k0 += BK) {
    __syncthreads();
#pragma unroll
    for (int q = 0; q < 4; ++q) { async16(pa[q], &As[dsto[q]]); pa[q] += BK; }
#pragma unroll
    for (int q = 0; q < 4; ++q) { async16(pb[q], &Bs[dsto[q]]); pb[q] += BK; }
    __syncthreads();

#pragma unroll
    for (int s = 0; s < 2; ++s) {
      bf16x8 af[4], bf[4];
#pragma unroll
      for (int i = 0; i < 4; ++i) {
        int row = wm + i * 16 + r;
        af[i] = *(const bf16x8*)&As[row * BK + ((((s << 2) + quad) ^ (row & 7)) << 3)];
      }
#pragma unroll
      for (int j = 0; j < 4; ++j) {
        int row = wn + j * 16 + r;
        bf[j] = *(const bf16x8*)&Bs[row * BK + ((((s << 2) + quad) ^ (row & 7)) << 3)];
      }
#pragma unroll
      for (int i = 0; i < 4; ++i)
#pragma unroll
        for (int j = 0; j < 4; ++j)
          acc[i][j] = __builtin_amdgcn_mfma_f32_16x16x32_bf16(af[i], bf[j], acc[i][j], 0, 0, 0);
    }
  }

#pragma unroll
  for (int i = 0; i < 4; ++i) {
    const int rowb = wm + i * 16 + quad * 4;
#pragma unroll
    for (int rr = 0; rr < 4; ++rr) {
      int t = s_idx[rowb + rr];
      if (t >= 0) {
        float* orow = Out + (size_t)t * DIM + n0 + wn + r;
#pragma unroll
        for (int j = 0; j < 4; ++j) unsafeAtomicAdd(&orow[j * 16], acc[i][j][rr]);
      }
    }
  }
}

__global__ void ws_marker_kernel(float* __restrict__ Out, float v) {
  if (threadIdx.x == 0 && blockIdx.x == 0) Out[0] = v;
}

extern "C" void kernel_launch(void* const* d_in, const int* in_sizes, int n_in,
                              void* d_out, int out_size, void* d_ws, size_t ws_size,
                              hipStream_t stream) {
  const float* x  = (const float*)d_in[0];
  const float* gw = (const float*)d_in[1];
  const float* w1 = (const float*)d_in[2];
  const float* w2 = (const float*)d_in[3];
  const float* w3 = (const float*)d_in[4];
  float* out = (float*)d_out;

  // ws: comb 128KiB | rt 128B | idxpool 66KiB | w1b(->w2b after ffn13) 20MiB |
  //     w3b 20MiB | Xb 16MiB | Hpool 82.5MiB   -> total ~145.4 MB
  const size_t WELEMS = (size_t)NEXP * HID * DIM;
  const size_t WBYTES = WELEMS * sizeof(u16);
  char* ws = (char*)d_ws;
  float* comb    = (float*)ws;
  int*   rt      = (int*)(ws + 131072);
  int*   idxpool = (int*)(ws + 131072 + 128);
  u16*   w1b     = (u16*)(ws + 131072 + 128 + (size_t)IDXCAP * 4);
  u16*   w2b     = w1b;                 // alias: w2 converted after ffn13
  u16*   w3b     = w1b + WELEMS;
  u16*   Xb      = w3b + WELEMS;
  u16*   Hpool   = Xb + (size_t)NTOK * DIM;

  const size_t need = 131072 + 128 + (size_t)IDXCAP * 4 + 2 * WBYTES +
                      (size_t)NTOK * DIM * sizeof(u16) +
                      (size_t)IDXCAP * HID * sizeof(u16);
  if (ws_size < need) {
    float v = 5000.0f + (float)((ws_size >> 20) > 999 ? 999 : (ws_size >> 20));
    ws_marker_kernel<<<dim3(1), dim3(64), 0, stream>>>(out, v);
    return;
  }

  zero_kernel<<<dim3(2048), dim3(256), 0, stream>>>(out, out_size / 4, rt);

  gate_kernel<<<dim3(NTOK / 4), dim3(256), 0, stream>>>(x, gw, comb, rt, Xb);
  scan_kernel<<<dim3(1), dim3(64), 0, stream>>>(rt);
  fill_kernel<<<dim3(NTOK / 256), dim3(256), 0, stream>>>(comb, rt, idxpool);

  {
    int n4each = (int)(WELEMS / 4);
    cvt13_kernel<<<dim3((2 * n4each + 255) / 256), dim3(256), 0, stream>>>(
        w1, w3, w1b, w3b, n4each);
  }

  ffn13_kernel<<<dim3(HID / BN, 64 * NEXP), dim3(256), 0, stream>>>(
      Xb, w1b, w3b, comb, idxpool, rt, Hpool);

  {
    int n4 = (int)(WELEMS / 4);
    cvt2_kernel<<<dim3((n4 + 255) / 256), dim3(256), 0, stream>>>(w2, w2b, n4);
  }

  ffn2_kernel<<<dim3(512 * NEXP), dim3(256), 0, stream>>>(Hpool, w2b, idxpool, rt, out);
}

// Round 5
// 522.771 us; speedup vs baseline: 1.7464x; 1.0858x over previous
//
#include <hip/hip_runtime.h>

typedef unsigned short u16;
typedef unsigned int   u32;

#define DIM  1024
#define HID  2560
#define NTOK 8192
#define NEXP 4

#define BM 128
#define BN 128
#define BK 64   // per barrier-pair; two 32-wide MFMA sub-tiles

#define IDXCAP 16896  // 2*NTOK + NEXP*BM padding rows

typedef __attribute__((ext_vector_type(8))) short bf16x8;
typedef __attribute__((ext_vector_type(4))) float f32x4;

// ---------- helpers ----------
__device__ __forceinline__ void async16(const void* g, void* l) {
  __builtin_amdgcn_global_load_lds((const __attribute__((address_space(1))) u32*)g,
                                   (__attribute__((address_space(3))) u32*)l,
                                   16, 0, 0);
}
__device__ __forceinline__ u16 f2bf(float f) {
  union { float f; u32 u; } c; c.f = f;
  u32 u = c.u;
  return (u16)((u + 0x7fffu + ((u >> 16) & 1u)) >> 16);   // RNE
}
__device__ __forceinline__ ushort4 cvt4(float4 v) {
  ushort4 o; o.x = f2bf(v.x); o.y = f2bf(v.y); o.z = f2bf(v.z); o.w = f2bf(v.w);
  return o;
}
// padded (128-aligned) prefix base for expert e, from live counts rt[0..3]
__device__ __forceinline__ int ebase(const int* __restrict__ rt, int e) {
  int b = 0;
#pragma unroll
  for (int q = 0; q < NEXP; ++q) {
    int p = (rt[q] + BM - 1) & ~(BM - 1);
    if (q < e) b += p;
  }
  return b;
}

// ---------- fp32 -> bf16: w1|w3 (before ffn13); block 0 also zeroes rt ----------
__global__ void cvt13_kernel(const float* __restrict__ w1, const float* __restrict__ w3,
                             u16* __restrict__ w1b, u16* __restrict__ w3b, int n4each,
                             int* __restrict__ rt) {
  if (blockIdx.x == 0 && threadIdx.x < 8) rt[threadIdx.x] = 0;  // cnt[4], cursor[4]
  int i = blockIdx.x * blockDim.x + threadIdx.x;
  if (i < n4each)
    ((ushort4*)w1b)[i] = cvt4(((const float4*)w1)[i]);
  else if (i < 2 * n4each)
    ((ushort4*)w3b)[i - n4each] = cvt4(((const float4*)w3)[i - n4each]);
}

// ---------- fp32 -> bf16: w2 (after ffn13; w2b aliases w1b) ----------
__global__ void cvt2_kernel(const float* __restrict__ w2, u16* __restrict__ w2b, int n4) {
  int i = blockIdx.x * blockDim.x + threadIdx.x;
  if (i < n4) ((ushort4*)w2b)[i] = cvt4(((const float4*)w2)[i]);
}

// ---------- gating: one wave/token; counts tokens/expert; writes Xb bf16; zeroes out ----------
__global__ void gate_kernel(const float* __restrict__ X, const float* __restrict__ GW,
                            float* __restrict__ comb, int* __restrict__ rt,
                            u16* __restrict__ Xb, float* __restrict__ out, int out_n) {
  __shared__ int s_cnt[NEXP];
  if (threadIdx.x < NEXP) s_cnt[threadIdx.x] = 0;

  int gtid = blockIdx.x * blockDim.x + threadIdx.x;

  // fused output zeroing (poison/replay-safe; ffn2 accumulates atomically later)
  {
    int n4 = out_n >> 2;
    int stride = gridDim.x * blockDim.x;
    float4 z = {0.f, 0.f, 0.f, 0.f};
    for (int j = gtid; j < n4; j += stride) ((float4*)out)[j] = z;
    if (gtid == 0)
      for (int j = n4 << 2; j < out_n; ++j) out[j] = 0.f;
  }
  __syncthreads();

  int tok  = gtid >> 6;
  int lane = gtid & 63;

  const float4* xv = (const float4*)(X + (size_t)tok * DIM + lane * 16);
  float4 x0 = xv[0], x1 = xv[1], x2 = xv[2], x3 = xv[3];

  // bf16 copy of X for the MFMA A-path
  ushort4* xb = (ushort4*)(Xb + (size_t)tok * DIM + lane * 16);
  xb[0] = cvt4(x0); xb[1] = cvt4(x1); xb[2] = cvt4(x2); xb[3] = cvt4(x3);

  float acc[NEXP];
#pragma unroll
  for (int e = 0; e < NEXP; ++e) {
    const float4* gv = (const float4*)(GW + e * DIM + lane * 16);
    float4 g0 = gv[0], g1 = gv[1], g2 = gv[2], g3 = gv[3];
    float s;
    s  = x0.x * g0.x + x0.y * g0.y + x0.z * g0.z + x0.w * g0.w;
    s += x1.x * g1.x + x1.y * g1.y + x1.z * g1.z + x1.w * g1.w;
    s += x2.x * g2.x + x2.y * g2.y + x2.z * g2.z + x2.w * g2.w;
    s += x3.x * g3.x + x3.y * g3.y + x3.z * g3.z + x3.w * g3.w;
    acc[e] = s;
  }
#pragma unroll
  for (int off = 32; off > 0; off >>= 1) {
#pragma unroll
    for (int e = 0; e < NEXP; ++e) acc[e] += __shfl_xor(acc[e], off);
  }
  if (lane == 0) {
    int i1 = 0;
#pragma unroll
    for (int e = 1; e < NEXP; ++e) if (acc[e] > acc[i1]) i1 = e;
    int i2 = -1;
#pragma unroll
    for (int e = 0; e < NEXP; ++e) {
      if (e == i1) continue;
      if (i2 < 0 || acc[e] > acc[i2]) i2 = e;
    }
    float m  = acc[i1];
    float e1 = __expf(acc[i1] - m), e2 = __expf(acc[i2] - m);
    float inv = 1.f / (e1 + e2);
    float w[NEXP] = {0.f, 0.f, 0.f, 0.f};
    w[i1] = e1 * inv; w[i2] = e2 * inv;
#pragma unroll
    for (int e = 0; e < NEXP; ++e) comb[(size_t)tok * NEXP + e] = w[e];
    atomicAdd(&s_cnt[i1], 1);
    atomicAdd(&s_cnt[i2], 1);
  }
  __syncthreads();
  if (threadIdx.x < NEXP) atomicAdd(&rt[threadIdx.x], s_cnt[threadIdx.x]);
}

// ---------- compact token lists per expert (ballot aggregation; bases computed locally) ----------
__global__ void fill_kernel(const float* __restrict__ comb, int* __restrict__ rt,
                            int* __restrict__ idxpool) {
  int t    = blockIdx.x * blockDim.x + threadIdx.x;
  int lane = threadIdx.x & 63;
  float4 c = ((const float4*)comb)[t];
  float cv[NEXP] = {c.x, c.y, c.z, c.w};
#pragma unroll
  for (int e = 0; e < NEXP; ++e) {
    bool sel = cv[e] > 0.f;
    unsigned long long b = __ballot(sel);
    int cw = __popcll(b);
    int bp = 0;
    if (lane == 0 && cw) bp = atomicAdd(&rt[4 + e], cw);
    bp = __shfl(bp, 0);
    if (sel) {
      int off = __popcll(b & ((1ull << lane) - 1ull));
      idxpool[ebase(rt, e) + bp + off] = t;
    }
  }
}

// Tile staging scheme (both GEMMs): LDS tile [128 rows][64 cols] bf16, 16B chunks.
// LDS dest LINEAR (global_load_lds wave-uniform-base + lane*16); bank-conflict fix
// via pre-swizzled GLOBAL source column: LDS(row,cc) holds G(row, cc ^ (row&7));
// the MFMA read applies the same XOR -> all 32 banks covered, 2-way max (free).

// ---------- GEMM1: h = comb * silu(x@w1^T) * (x@w3^T), gathered rows ----------
__global__ __launch_bounds__(256, 2) void ffn13_kernel(
    const u16* __restrict__ Xb, const u16* __restrict__ W1,
    const u16* __restrict__ W3, const float* __restrict__ combp,
    const int* __restrict__ idxpool, const int* __restrict__ rt,
    u16* __restrict__ Hpool) {
  const int e   = blockIdx.y >> 6;
  const int mb  = blockIdx.y & 63;
  const int cnt = rt[e];
  const int m0  = mb * BM;
  if (m0 >= cnt) return;
  const int rbase = ebase(rt, e);
  const int n0    = blockIdx.x * BN;

  __shared__ __align__(16) u16 As [BM * BK];
  __shared__ __align__(16) u16 B1s[BN * BK];
  __shared__ __align__(16) u16 B3s[BN * BK];
  __shared__ float s_comb[BM];
  __shared__ int   s_idx [BM];

  const int tid  = threadIdx.x;
  const int wave = tid >> 6;
  const int lane = tid & 63;

  if (tid < BM) {
    int m = m0 + tid;
    int t = (m < cnt) ? idxpool[rbase + m] : 0;
    s_idx[tid]  = t;
    s_comb[tid] = combp[(size_t)t * NEXP + e];
  }
  __syncthreads();

  const u16* W1e = W1 + (size_t)e * HID * DIM;
  const u16* W3e = W3 + (size_t)e * HID * DIM;

  const int scc = (((tid & 7) ^ ((tid >> 3) & 7)) << 3);  // swizzled src col (elems)
  const int r0  = tid >> 3;
  const u16 *pA[4], *pB1[4], *pB3[4];
  int dsto[4];
#pragma unroll
  for (int q = 0; q < 4; ++q) {
    int row = r0 + 32 * q;
    pA[q]   = Xb  + (size_t)s_idx[row] * DIM + scc;
    pB1[q]  = W1e + (size_t)(n0 + row) * DIM + scc;
    pB3[q]  = W3e + (size_t)(n0 + row) * DIM + scc;
    dsto[q] = (tid + 256 * q) * 8;
  }

  const int wm = (wave >> 1) * 64, wn = (wave & 1) * 64;
  const int quad = lane >> 4, r = lane & 15;

  f32x4 acc1[4][4], acc3[4][4];
#pragma unroll
  for (int i = 0; i < 4; ++i)
#pragma unroll
    for (int j = 0; j < 4; ++j) {
      acc1[i][j] = (f32x4){0.f, 0.f, 0.f, 0.f};
      acc3[i][j] = (f32x4){0.f, 0.f, 0.f, 0.f};
    }

  for (int k0 = 0; k0 < DIM; k0 += BK) {
    __syncthreads();
#pragma unroll
    for (int q = 0; q < 4; ++q) { async16(pA[q],  &As [dsto[q]]); pA[q]  += BK; }
#pragma unroll
    for (int q = 0; q < 4; ++q) { async16(pB1[q], &B1s[dsto[q]]); pB1[q] += BK; }
#pragma unroll
    for (int q = 0; q < 4; ++q) { async16(pB3[q], &B3s[dsto[q]]); pB3[q] += BK; }
    __syncthreads();

#pragma unroll
    for (int s = 0; s < 2; ++s) {
      bf16x8 af[4], b1f[4], b3f[4];
#pragma unroll
      for (int i = 0; i < 4; ++i) {
        int row = wm + i * 16 + r;
        af[i] = *(const bf16x8*)&As[row * BK + ((((s << 2) + quad) ^ (row & 7)) << 3)];
      }
#pragma unroll
      for (int j = 0; j < 4; ++j) {
        int row = wn + j * 16 + r;
        int cc  = (((s << 2) + quad) ^ (row & 7)) << 3;
        b1f[j] = *(const bf16x8*)&B1s[row * BK + cc];
        b3f[j] = *(const bf16x8*)&B3s[row * BK + cc];
      }
#pragma unroll
      for (int i = 0; i < 4; ++i)
#pragma unroll
        for (int j = 0; j < 4; ++j) {
          acc1[i][j] = __builtin_amdgcn_mfma_f32_16x16x32_bf16(af[i], b1f[j], acc1[i][j], 0, 0, 0);
          acc3[i][j] = __builtin_amdgcn_mfma_f32_16x16x32_bf16(af[i], b3f[j], acc3[i][j], 0, 0, 0);
        }
    }
  }

#pragma unroll
  for (int i = 0; i < 4; ++i) {
    const int rowb = wm + i * 16 + quad * 4;
#pragma unroll
    for (int rr = 0; rr < 4; ++rr) {
      const float cw = s_comb[rowb + rr];
      u16* orow = Hpool + (size_t)(rbase + m0 + rowb + rr) * HID + n0 + wn + r;
#pragma unroll
      for (int j = 0; j < 4; ++j) {
        float v1v = acc1[i][j][rr];
        float v3v = acc3[i][j][rr];
        float sig = 1.f / (1.f + __expf(-v1v));
        orow[j * 16] = f2bf(cw * (v1v * sig * v3v));
      }
    }
  }
}

// ---------- GEMM2: out[token] += h_row @ w2_e^T (compact rows, atomic scatter) ----------
// Dynamic tile map: grid-stride over SUM_e Mb_e*8 tiles, mb fastest within an expert.
// All blocks participate regardless of per-expert counts (fixes the half-idle-XCD
// bug of the static stripe map). When Mb_e%8==0 the 8 nb-readers of one H A-panel
// land on one XCD (stride Mb in tile id -> same id mod 8) -> per-XCD L2 reuse of H.
__global__ __launch_bounds__(256, 2) void ffn2_kernel(
    const u16* __restrict__ Hpool, const u16* __restrict__ W2b,
    const int* __restrict__ idxpool, const int* __restrict__ rt,
    float* __restrict__ Out) {
  __shared__ __align__(16) u16 As[BM * BK];
  __shared__ __align__(16) u16 Bs[BN * BK];
  __shared__ int s_idx[BM];

  int cnt_[NEXP], Mb_[NEXP], base_[NEXP], rb_[NEXP];
  int total = 0, rb = 0;
#pragma unroll
  for (int e = 0; e < NEXP; ++e) {
    cnt_[e]  = rt[e];
    Mb_[e]   = (cnt_[e] + BM - 1) >> 7;
    base_[e] = total;
    rb_[e]   = rb;
    total   += Mb_[e] * (DIM / BN);
    rb      += (cnt_[e] + BM - 1) & ~(BM - 1);
  }

  const int tid  = threadIdx.x;
  const int wave = tid >> 6;
  const int lane = tid & 63;
  const int scc  = (((tid & 7) ^ ((tid >> 3) & 7)) << 3);
  const int r0   = tid >> 3;
  const int wm = (wave >> 1) * 64, wn = (wave & 1) * 64;
  const int quad = lane >> 4, r = lane & 15;

  for (int t = blockIdx.x; t < total; t += gridDim.x) {
    int e = 0;
#pragma unroll
    for (int q = 1; q < NEXP; ++q) if (t >= base_[q]) e = q;
    const int tl  = t - base_[e];
    const int Mb  = Mb_[e];
    const int mb  = tl % Mb;
    const int nb  = tl / Mb;
    const int cnt = cnt_[e];
    const int rbase = rb_[e];
    const int m0 = mb * BM;
    const int n0 = nb * BN;

    __syncthreads();  // protect s_idx/LDS vs previous tile's epilogue
    if (tid < BM) {
      int m = m0 + tid;
      s_idx[tid] = (m < cnt) ? idxpool[rbase + m] : -1;
    }

    const u16 *pa[4], *pb[4];
    int dsto[4];
#pragma unroll
    for (int q = 0; q < 4; ++q) {
      int row = r0 + 32 * q;
      pa[q]   = Hpool + (size_t)(rbase + m0 + row) * HID + scc;
      pb[q]   = W2b + ((size_t)e * DIM + n0 + row) * HID + scc;
      dsto[q] = (tid + 256 * q) * 8;
    }

    f32x4 acc[4][4];
#pragma unroll
    for (int i = 0; i < 4; ++i)
#pragma unroll
      for (int j = 0; j < 4; ++j) acc[i][j] = (f32x4){0.f, 0.f, 0.f, 0.f};

    for (int k0 = 0; k0 < HID; k0 += BK) {
      __syncthreads();
#pragma unroll
      for (int q = 0; q < 4; ++q) { async16(pa[q], &As[dsto[q]]); pa[q] += BK; }
#pragma unroll
      for (int q = 0; q < 4; ++q) { async16(pb[q], &Bs[dsto[q]]); pb[q] += BK; }
      __syncthreads();

#pragma unroll
      for (int s = 0; s < 2; ++s) {
        bf16x8 af[4], bf[4];
#pragma unroll
        for (int i = 0; i < 4; ++i) {
          int row = wm + i * 16 + r;
          af[i] = *(const bf16x8*)&As[row * BK + ((((s << 2) + quad) ^ (row & 7)) << 3)];
        }
#pragma unroll
        for (int j = 0; j < 4; ++j) {
          int row = wn + j * 16 + r;
          bf[j] = *(const bf16x8*)&Bs[row * BK + ((((s << 2) + quad) ^ (row & 7)) << 3)];
        }
#pragma unroll
        for (int i = 0; i < 4; ++i)
#pragma unroll
          for (int j = 0; j < 4; ++j)
            acc[i][j] = __builtin_amdgcn_mfma_f32_16x16x32_bf16(af[i], bf[j], acc[i][j], 0, 0, 0);
      }
    }

#pragma unroll
    for (int i = 0; i < 4; ++i) {
      const int rowb = wm + i * 16 + quad * 4;
#pragma unroll
      for (int rr = 0; rr < 4; ++rr) {
        int tk = s_idx[rowb + rr];
        if (tk >= 0) {
          float* orow = Out + (size_t)tk * DIM + n0 + wn + r;
#pragma unroll
          for (int j = 0; j < 4; ++j) unsafeAtomicAdd(&orow[j * 16], acc[i][j][rr]);
        }
      }
    }
  }
}

__global__ void ws_marker_kernel(float* __restrict__ Out, float v) {
  if (threadIdx.x == 0 && blockIdx.x == 0) Out[0] = v;
}

extern "C" void kernel_launch(void* const* d_in, const int* in_sizes, int n_in,
                              void* d_out, int out_size, void* d_ws, size_t ws_size,
                              hipStream_t stream) {
  const float* x  = (const float*)d_in[0];
  const float* gw = (const float*)d_in[1];
  const float* w1 = (const float*)d_in[2];
  const float* w2 = (const float*)d_in[3];
  const float* w3 = (const float*)d_in[4];
  float* out = (float*)d_out;

  // ws: comb 128KiB | rt 128B | idxpool 66KiB | w1b(->w2b after ffn13) 20MiB |
  //     w3b 20MiB | Xb 16MiB | Hpool 82.5MiB   -> total ~145.4 MB
  const size_t WELEMS = (size_t)NEXP * HID * DIM;
  const size_t WBYTES = WELEMS * sizeof(u16);
  char* ws = (char*)d_ws;
  float* comb    = (float*)ws;
  int*   rt      = (int*)(ws + 131072);
  int*   idxpool = (int*)(ws + 131072 + 128);
  u16*   w1b     = (u16*)(ws + 131072 + 128 + (size_t)IDXCAP * 4);
  u16*   w2b     = w1b;                 // alias: w2 converted after ffn13
  u16*   w3b     = w1b + WELEMS;
  u16*   Xb      = w3b + WELEMS;
  u16*   Hpool   = Xb + (size_t)NTOK * DIM;

  const size_t need = 131072 + 128 + (size_t)IDXCAP * 4 + 2 * WBYTES +
                      (size_t)NTOK * DIM * sizeof(u16) +
                      (size_t)IDXCAP * HID * sizeof(u16);
  if (ws_size < need) {
    float v = 5000.0f + (float)((ws_size >> 20) > 999 ? 999 : (ws_size >> 20));
    ws_marker_kernel<<<dim3(1), dim3(64), 0, stream>>>(out, v);
    return;
  }

  {
    int n4each = (int)(WELEMS / 4);
    cvt13_kernel<<<dim3((2 * n4each + 255) / 256), dim3(256), 0, stream>>>(
        w1, w3, w1b, w3b, n4each, rt);
  }

  gate_kernel<<<dim3(NTOK / 4), dim3(256), 0, stream>>>(x, gw, comb, rt, Xb,
                                                        out, out_size / 4);
  fill_kernel<<<dim3(NTOK / 256), dim3(256), 0, stream>>>(comb, rt, idxpool);

  ffn13_kernel<<<dim3(HID / BN, 64 * NEXP), dim3(256), 0, stream>>>(
      Xb, w1b, w3b, comb, idxpool, rt, Hpool);

  {
    int n4 = (int)(WELEMS / 4);
    cvt2_kernel<<<dim3((n4 + 255) / 256), dim3(256), 0, stream>>>(w2, w2b, n4);
  }

  ffn2_kernel<<<dim3(2048), dim3(256), 0, stream>>>(Hpool, w2b, idxpool, rt, out);
}